// Round 5
// baseline (462.590 us; speedup 1.0000x reference)
//
#include <hip/hip_runtime.h>
#include <math.h>

#define NB 8
#define CC 14
#define HH 512
#define WW 512
#define HW (HH*WW)          // 262144
#define NHW (NB*HW)         // 2097152
#define WPR 8               // uint64 words per row (512 bits)
#define WPI (HH*WPR)        // 4096 words per image
#define KSPLIT 32
#define KCHUNK (HW/KSPLIT)  // 8192
#define KBLOCKS (NB*CC*KSPLIT)  // 3584

typedef unsigned long long u64;

// ---------------- Stage A: teacher argmax -> uint8 gray map (x4 vec) -------
__global__ __launch_bounds__(256) void k_argmax(const float* __restrict__ T,
                                                uchar4* __restrict__ tmap4,
                                                unsigned* __restrict__ cnt) {
    if (blockIdx.x == 0 && threadIdx.x == 0) *cnt = 0;   // re-arm last-block counter
    int i4 = blockIdx.x * blockDim.x + threadIdx.x;      // 4-pixel group id
    if (i4 >= NHW / 4) return;
    int n  = i4 / (HW / 4);
    int p4 = i4 - n * (HW / 4);
    const float4* base = (const float4*)(T + (size_t)n * CC * HW) + p4;
    float4 best = base[0];
    int b0 = 0, b1 = 0, b2 = 0, b3 = 0;
#pragma unroll
    for (int c = 1; c < CC; ++c) {
        float4 v = base[(size_t)c * (HW / 4)];
        if (v.x > best.x) { best.x = v.x; b0 = c; }
        if (v.y > best.y) { best.y = v.y; b1 = c; }
        if (v.z > best.z) { best.z = v.z; b2 = c; }
        if (v.w > best.w) { best.w = v.w; b3 = c; }
    }
    uchar4 g;
    g.x = (unsigned char)(((float)b0 / 13.0f) * 255.0f);  // match op order: /13 then *255, trunc
    g.y = (unsigned char)(((float)b1 / 13.0f) * 255.0f);
    g.z = (unsigned char)(((float)b2 / 13.0f) * 255.0f);
    g.w = (unsigned char)(((float)b3 / 13.0f) * 255.0f);
    tmap4[i4] = g;
}

// ------- Stage B: fused Sobel(replicate) + NMS(zero-pad) -> weak/strong bits
// grid (8,8,NB): 64x64 tile per block; tm halo 2, mag/sect halo 1.
__global__ __launch_bounds__(256) void k_sobel_nms(const unsigned char* __restrict__ tmap,
                                                   u64* __restrict__ weakBits,
                                                   u64* __restrict__ strongBits) {
    int tx = blockIdx.x, ty = blockIdx.y, n = blockIdx.z;
    int x0 = tx * 64, y0 = ty * 64;
    __shared__ unsigned char tm[68 * 68];
    __shared__ unsigned short ms[66 * 66];
    int tid = threadIdx.x;
    const unsigned char* im = tmap + (size_t)n * HW;

    // phase 1: load 68x68 tmap tile, replicate-clamped at image borders
    for (int idx = tid; idx < 68 * 68; idx += 256) {
        int r = idx / 68, c = idx - r * 68;
        int yy = y0 - 2 + r; yy = yy < 0 ? 0 : (yy > HH - 1 ? HH - 1 : yy);
        int xx = x0 - 2 + c; xx = xx < 0 ? 0 : (xx > WW - 1 ? WW - 1 : xx);
        tm[idx] = im[yy * WW + xx];
    }
    __syncthreads();

    // phase 2: sobel -> (mag<<2)|sector for 66x66 (halo 1 for NMS)
    for (int idx = tid; idx < 66 * 66; idx += 256) {
        int r = idx / 66, c = idx - r * 66;
        const unsigned char* t0 = tm + r * 68 + c;   // top-left of 3x3
        int a00 = t0[0],   a01 = t0[1],   a02 = t0[2];
        int a10 = t0[68],                 a12 = t0[70];
        int a20 = t0[136], a21 = t0[137], a22 = t0[138];
        int gx = (a02 - a00) + 2 * (a12 - a10) + (a22 - a20);
        int gy = (a20 - a00) + 2 * (a21 - a01) + (a22 - a02);
        int m = (gx < 0 ? -gx : gx) + (gy < 0 ? -gy : gy);   // L1 magnitude, exact int
        float ang = atan2f((float)gy, (float)gx) * 57.29577951308232f;
        ang = fmodf(ang, 180.0f);
        if (ang < 0.0f) ang += 180.0f;
        int s;
        if (ang < 22.5f || ang >= 157.5f) s = 0;
        else if (ang < 67.5f)             s = 1;
        else if (ang < 112.5f)            s = 2;
        else                              s = 3;
        ms[idx] = (unsigned short)((m << 2) | s);
    }
    __syncthreads();

    // phase 3: NMS + ballot-pack; lane = x-in-tile (tile is one 64-bit word col)
    int lane = tid & 63;
    int warp = tid >> 6;
#pragma unroll
    for (int it = 0; it < 16; ++it) {
        int row = it * 4 + warp;
        int gy_ = y0 + row, gx_ = x0 + lane;
        int v = ms[(row + 1) * 66 + (lane + 1)];
        int mc = v >> 2, s = v & 3;
        int dy1, dx1, dy2, dx2;
        if (s == 0)      { dy1 = 0;  dx1 = 1;  dy2 = 0; dx2 = -1; }
        else if (s == 1) { dy1 = -1; dx1 = 1;  dy2 = 1; dx2 = -1; }
        else if (s == 2) { dy1 = -1; dx1 = 0;  dy2 = 1; dx2 = 0;  }
        else             { dy1 = -1; dx1 = -1; dy2 = 1; dx2 = 1;  }
        int y1 = gy_ + dy1, x1 = gx_ + dx1, y2 = gy_ + dy2, x2 = gx_ + dx2;
        int n1 = (y1 < 0 || y1 >= HH || x1 < 0 || x1 >= WW)
                 ? 0 : (ms[(row + 1 + dy1) * 66 + (lane + 1 + dx1)] >> 2);
        int n2 = (y2 < 0 || y2 >= HH || x2 < 0 || x2 >= WW)
                 ? 0 : (ms[(row + 1 + dy2) * 66 + (lane + 1 + dx2)] >> 2);
        int nms = (mc >= n1 && mc >= n2) ? mc : 0;
        u64 wm = __ballot(nms > 10);
        u64 sm = __ballot(nms > 50);
        if (lane == 0) {
            size_t w = (size_t)n * WPI + gy_ * WPR + tx;
            weakBits[w]   = wm;
            strongBits[w] = sm;
        }
    }
}

// ---- Stage C+D+E: 16 hysteresis iters + 10x10 dilate + 10x10 blur, fused --
// 16 tiles/image (32 rows each) + 26-row halo. Exactness: 16 grow iters
// contaminate 16 rows from the unknown tile edge -> A exact on local rows
// [16, TROWS-17] = [16, 67]; vertical dilate row d (d in [0,41], global
// t0r-5+d) reads horizontally-dilated B rows [d+16, d+25] in [16, 66] ✓.
// Blur of the 32 output rows needs exactly dil rows global [t0r-5, t0r+36]
// (reflect101 at image borders maps back inside this range).
#define TR 32
#define HALO 26
#define TROWS (TR + 2*HALO)    // 84
#define TWORDS (TROWS * WPR)   // 672
__global__ __launch_bounds__(1024) void k_hyst_dil_blur(const u64* __restrict__ strongBits,
                                                        const u64* __restrict__ weakBits,
                                                        unsigned char* __restrict__ E) {
    int tile = blockIdx.x & 15;
    int n    = blockIdx.x >> 4;
    int t0r  = tile * TR;
    int g0   = t0r - HALO;                 // virtual first row of tile
    __shared__ u64 A[TWORDS];
    __shared__ u64 B[TWORDS];
    __shared__ u64 Wl[TWORDS];             // weak bits; reused as D (dilated) later
    __shared__ unsigned char rc[(TR + 10) * 512]; // horizontal blur rowcounts
    int tid = threadIdx.x;

    if (tid < TWORDS) {
        int vr = g0 + (tid >> 3);
        int w  = tid & 7;
        u64 sv = 0, wv = 0;
        if (vr >= 0 && vr < HH) {
            sv = strongBits[(size_t)n * WPI + vr * WPR + w];
            wv = weakBits  [(size_t)n * WPI + vr * WPR + w];
        }
        A[tid] = sv;
        Wl[tid] = wv;
    }
    __syncthreads();

#pragma unroll 1
    for (int it = 0; it < 16; ++it) {
        const u64* src = (it & 1) ? B : A;
        u64*       dst = (it & 1) ? A : B;
        if (tid < TWORDS) {
            int r = tid >> 3;
            int w = tid & 7;
            u64 c  = src[tid];
            u64 up = (r > 0)         ? src[tid - 8] : 0;
            u64 dn = (r < TROWS - 1) ? src[tid + 8] : 0;
            u64 a = c | up | dn;
            u64 pL = 0, pR = 0;
            if (w > 0) {
                u64 cl = src[tid - 1];
                u64 ul = (r > 0)         ? src[tid - 9] : 0;
                u64 dl = (r < TROWS - 1) ? src[tid + 7] : 0;
                pL = cl | ul | dl;
            }
            if (w < 7) {
                u64 cr = src[tid + 1];
                u64 ur = (r > 0)         ? src[tid - 7] : 0;
                u64 dr = (r < TROWS - 1) ? src[tid + 9] : 0;
                pR = cr | ur | dr;
            }
            u64 g = a | (a << 1) | (pL >> 63) | (a >> 1) | (pR << 63);
            dst[tid] = g & Wl[tid];
        }
        __syncthreads();
    }
    // result (after 16 iters) is in A

    // dilate horizontal: window [x-5, x+4]
    if (tid < TWORDS) {
        int w = tid & 7;
        u64 v  = A[tid];
        u64 p  = (w > 0) ? A[tid - 1] : 0;
        u64 nx = (w < 7) ? A[tid + 1] : 0;
        u64 o = v;
#pragma unroll
        for (int d = 1; d <= 5; ++d) o |= (v << d) | (p >> (64 - d));
#pragma unroll
        for (int d = 1; d <= 4; ++d) o |= (v >> d) | (nx << (64 - d));
        B[tid] = o;
    }
    __syncthreads();

    // dilate vertical: window [y-5, y+4], zero-pad beyond image (A/B are 0
    // there). D row d (d in [0,TR+10)) = dil at global row t0r-5+d, local d+21.
    u64* D = Wl;   // weak bits dead now; reuse
    if (tid < (TR + 10) * WPR) {
        int d = tid >> 3;
        int w = tid & 7;
        int r = d + HALO - 5;
        u64 o = 0;
#pragma unroll
        for (int dy = -5; dy <= 4; ++dy) o |= B[(r + dy) * WPR + w];
        D[d * WPR + w] = o;
    }
    __syncthreads();

    // horizontal 10-bit window popcount per pixel (reflect101 at x edges)
    for (int idx = tid; idx < (TR + 10) * 512; idx += 1024) {
        int r = idx >> 9;
        int x = idx & 511;
        int c;
        if (x >= 5 && x <= 507) {
            int b = x - 5, wd = b >> 6, off = b & 63;
            u64 v = D[r * WPR + wd] >> off;
            if (off && wd < 7) v |= D[r * WPR + wd + 1] << (64 - off);
            c = __popcll(v & 0x3FFull);
        } else {
            c = 0;
            for (int dx = -5; dx <= 4; ++dx) {
                int xx = x + dx;
                xx = xx < 0 ? -xx : (xx > WW - 1 ? 2 * (WW - 1) - xx : xx);
                c += (int)((D[r * WPR + (xx >> 6)] >> (xx & 63)) & 1ull);
            }
        }
        rc[idx] = (unsigned char)c;
    }
    __syncthreads();

    // vertical 10-row sum (reflect101 rows at image borders), quantize, store
    // E byte k: edge value = k/255 with k = rint(255*cnt/100) (exact int-val float)
    for (int idx = tid; idx < TR * 512; idx += 1024) {
        int yy = idx >> 9;
        int x  = idx & 511;
        int gy = t0r + yy;
        int sum = 0;
        if (gy >= 5 && gy <= HH - 5) {          // window fully inside image
#pragma unroll
            for (int k = 0; k < 10; ++k) sum += rc[(yy + k) * 512 + x];
        } else {
#pragma unroll
            for (int k = 0; k < 10; ++k) {
                int v  = gy - 5 + k;
                int rv = v < 0 ? -v : (v > HH - 1 ? 2 * (HH - 1) - v : v);
                sum += rc[(rv - (t0r - 5)) * 512 + x];
            }
        }
        float b = rintf((255.0f * (float)sum) / 100.0f);   // round half to even
        E[(size_t)n * HW + gy * WW + x] = (unsigned char)b;
    }
}

// ---- Stage F: per-(n,c) KL partials + fused last-block finalize -----------
// |e*pred| <= ~6 so exp() never overflows; Z <= ~5e7 fits float easily.
// loss_nc = Wt/Zt - log Zt + log Zs with Zt=sum e^t, Wt=sum e^t (t-s), Zs=sum e^s
__global__ __launch_bounds__(256) void k_kl_partial(const float* __restrict__ S,
                                                    const float* __restrict__ T,
                                                    const unsigned char* __restrict__ E,
                                                    double* __restrict__ partial,
                                                    unsigned* __restrict__ cnt,
                                                    float* __restrict__ out) {
    int cidx  = blockIdx.x;   // n*CC + c
    int split = blockIdx.y;   // 0..KSPLIT-1
    int n = cidx / CC;
    const float4* Tp = (const float4*)(T + (size_t)cidx * HW + (size_t)split * KCHUNK);
    const float4* Sp = (const float4*)(S + (size_t)cidx * HW + (size_t)split * KCHUNK);
    const uchar4* Ep = (const uchar4*)(E + (size_t)n    * HW + (size_t)split * KCHUNK);
    int tid = threadIdx.x;

    float Zt = 0.0f, Wt = 0.0f, Zs = 0.0f;
#pragma unroll
    for (int k = 0; k < KCHUNK / 4 / 256; ++k) {       // 8 iterations
        int j = k * 256 + tid;
        float4 t4 = Tp[j];
        float4 s4 = Sp[j];
        uchar4 e4 = Ep[j];
#pragma unroll
        for (int u = 0; u < 4; ++u) {
            float e = (float)((&e4.x)[u]) / 255.0f;    // == b/255.0f bit-exact
            float t = e * (&t4.x)[u];
            float s = e * (&s4.x)[u];
            float et = __expf(t);
            Zt += et;
            Wt += et * (t - s);
            Zs += __expf(s);
        }
    }

    // wave-level shuffle reduction (double), then 4-wave LDS combine
    double zt = (double)Zt, wt = (double)Wt, zs = (double)Zs;
#pragma unroll
    for (int off = 32; off > 0; off >>= 1) {
        zt += __shfl_down(zt, off);
        wt += __shfl_down(wt, off);
        zs += __shfl_down(zs, off);
    }
    __shared__ double wr[4][3];
    int wv = tid >> 6, ln = tid & 63;
    if (ln == 0) { wr[wv][0] = zt; wr[wv][1] = wt; wr[wv][2] = zs; }
    __syncthreads();
    if (tid == 0) {
        double* o = partial + ((size_t)cidx * KSPLIT + split) * 3;
        o[0] = wr[0][0] + wr[1][0] + wr[2][0] + wr[3][0];
        o[1] = wr[0][1] + wr[1][1] + wr[2][1] + wr[3][1];
        o[2] = wr[0][2] + wr[1][2] + wr[2][2] + wr[3][2];
    }

    // -------- last-block-done final reduce (deterministic) --------
    __shared__ unsigned sdone;
    if (tid == 0) {
        __threadfence();                       // release our partial
        unsigned old = atomicAdd(cnt, 1u);     // device-scope
        sdone = (old == (unsigned)(KBLOCKS - 1));
    }
    __syncthreads();
    if (sdone) {
        __threadfence();                       // acquire all partials
        double loss = 0.0;
        if (tid < NB * CC) {
            double Ztd = 0.0, Wtd = 0.0, Zsd = 0.0;
            for (int sp = 0; sp < KSPLIT; ++sp) {
                const double* p = partial + ((size_t)tid * KSPLIT + sp) * 3;
                Ztd += p[0]; Wtd += p[1]; Zsd += p[2];
            }
            loss = Wtd / Ztd - log(Ztd) + log(Zsd);
        }
        __shared__ double red[256];
        red[tid] = loss;
        __syncthreads();
        for (int off = 128; off > 0; off >>= 1) {
            if (tid < off) red[tid] += red[tid + off];
            __syncthreads();
        }
        if (tid == 0) out[0] = (float)(red[0] / (double)(NB * CC));  // T^2 = 1
    }
}

extern "C" void kernel_launch(void* const* d_in, const int* in_sizes, int n_in,
                              void* d_out, int out_size, void* d_ws, size_t ws_size,
                              hipStream_t stream) {
    const float* S = (const float*)d_in[0];   // preds_S
    const float* T = (const float*)d_in[1];   // preds_T
    float* out = (float*)d_out;

    char* ws = (char*)d_ws;
    unsigned char* e_buf      = (unsigned char*)(ws);                        // 2 MB (uint8)
    unsigned char* tmap       = (unsigned char*)(ws + (size_t)NHW);          // 2 MB
    u64*           weakBits   = (u64*)(ws + (size_t)NHW * 2);                // 256 KB
    u64*           strongBits = (u64*)(ws + (size_t)NHW * 2 + (NHW/8));      // 256 KB
    double*        partial    = (double*)(ws + (size_t)NHW * 2 + 2*(NHW/8)); // 86 KB
    unsigned*      cnt        = (unsigned*)(ws + (size_t)NHW * 2 + 2*(NHW/8) + 90112);

    k_argmax<<<dim3(NHW / 4 / 256), dim3(256), 0, stream>>>(T, (uchar4*)tmap, cnt);
    k_sobel_nms<<<dim3(8, 8, NB), dim3(256), 0, stream>>>(tmap, weakBits, strongBits);
    k_hyst_dil_blur<<<dim3(NB * 16), dim3(1024), 0, stream>>>(strongBits, weakBits, e_buf);
    k_kl_partial<<<dim3(NB * CC, KSPLIT), dim3(256), 0, stream>>>(S, T, e_buf, partial, cnt, out);
    (void)in_sizes; (void)n_in; (void)out_size; (void)ws_size;
}

// Round 6
// 299.970 us; speedup vs baseline: 1.5421x; 1.5421x over previous
//
#include <hip/hip_runtime.h>
#include <math.h>

#define NB 8
#define CC 14
#define HH 512
#define WW 512
#define HW (HH*WW)          // 262144
#define NHW (NB*HW)         // 2097152
#define WPR 8               // uint64 words per row (512 bits)
#define WPI (HH*WPR)        // 4096 words per image
#define KSPLIT 32
#define KCHUNK (HW/KSPLIT)  // 8192

typedef unsigned long long u64;

// ---------------- Stage A: teacher argmax -> uint8 gray map (x4 vec) -------
__global__ __launch_bounds__(256) void k_argmax(const float* __restrict__ T,
                                                uchar4* __restrict__ tmap4) {
    int i4 = blockIdx.x * blockDim.x + threadIdx.x;      // 4-pixel group id
    if (i4 >= NHW / 4) return;
    int n  = i4 / (HW / 4);
    int p4 = i4 - n * (HW / 4);
    const float4* base = (const float4*)(T + (size_t)n * CC * HW) + p4;
    float4 best = base[0];
    int b0 = 0, b1 = 0, b2 = 0, b3 = 0;
#pragma unroll
    for (int c = 1; c < CC; ++c) {
        float4 v = base[(size_t)c * (HW / 4)];
        if (v.x > best.x) { best.x = v.x; b0 = c; }
        if (v.y > best.y) { best.y = v.y; b1 = c; }
        if (v.z > best.z) { best.z = v.z; b2 = c; }
        if (v.w > best.w) { best.w = v.w; b3 = c; }
    }
    uchar4 g;
    g.x = (unsigned char)(((float)b0 / 13.0f) * 255.0f);  // match op order: /13 then *255, trunc
    g.y = (unsigned char)(((float)b1 / 13.0f) * 255.0f);
    g.z = (unsigned char)(((float)b2 / 13.0f) * 255.0f);
    g.w = (unsigned char)(((float)b3 / 13.0f) * 255.0f);
    tmap4[i4] = g;
}

// ------- Stage B: fused Sobel(replicate) + NMS(zero-pad) -> weak/strong bits
// grid (8,8,NB): 64x64 tile per block; tm halo 2, mag/sect halo 1.
__global__ __launch_bounds__(256) void k_sobel_nms(const unsigned char* __restrict__ tmap,
                                                   u64* __restrict__ weakBits,
                                                   u64* __restrict__ strongBits) {
    int tx = blockIdx.x, ty = blockIdx.y, n = blockIdx.z;
    int x0 = tx * 64, y0 = ty * 64;
    __shared__ unsigned char tm[68 * 68];
    __shared__ unsigned short ms[66 * 66];
    int tid = threadIdx.x;
    const unsigned char* im = tmap + (size_t)n * HW;

    // phase 1: load 68x68 tmap tile, replicate-clamped at image borders
    for (int idx = tid; idx < 68 * 68; idx += 256) {
        int r = idx / 68, c = idx - r * 68;
        int yy = y0 - 2 + r; yy = yy < 0 ? 0 : (yy > HH - 1 ? HH - 1 : yy);
        int xx = x0 - 2 + c; xx = xx < 0 ? 0 : (xx > WW - 1 ? WW - 1 : xx);
        tm[idx] = im[yy * WW + xx];
    }
    __syncthreads();

    // phase 2: sobel -> (mag<<2)|sector for 66x66 (halo 1 for NMS)
    for (int idx = tid; idx < 66 * 66; idx += 256) {
        int r = idx / 66, c = idx - r * 66;
        const unsigned char* t0 = tm + r * 68 + c;   // top-left of 3x3
        int a00 = t0[0],   a01 = t0[1],   a02 = t0[2];
        int a10 = t0[68],                 a12 = t0[70];
        int a20 = t0[136], a21 = t0[137], a22 = t0[138];
        int gx = (a02 - a00) + 2 * (a12 - a10) + (a22 - a20);
        int gy = (a20 - a00) + 2 * (a21 - a01) + (a22 - a02);
        int m = (gx < 0 ? -gx : gx) + (gy < 0 ? -gy : gy);   // L1 magnitude, exact int
        float ang = atan2f((float)gy, (float)gx) * 57.29577951308232f;
        ang = fmodf(ang, 180.0f);
        if (ang < 0.0f) ang += 180.0f;
        int s;
        if (ang < 22.5f || ang >= 157.5f) s = 0;
        else if (ang < 67.5f)             s = 1;
        else if (ang < 112.5f)            s = 2;
        else                              s = 3;
        ms[idx] = (unsigned short)((m << 2) | s);
    }
    __syncthreads();

    // phase 3: NMS + ballot-pack; lane = x-in-tile (tile is one 64-bit word col)
    int lane = tid & 63;
    int warp = tid >> 6;
#pragma unroll
    for (int it = 0; it < 16; ++it) {
        int row = it * 4 + warp;
        int gy_ = y0 + row, gx_ = x0 + lane;
        int v = ms[(row + 1) * 66 + (lane + 1)];
        int mc = v >> 2, s = v & 3;
        int dy1, dx1, dy2, dx2;
        if (s == 0)      { dy1 = 0;  dx1 = 1;  dy2 = 0; dx2 = -1; }
        else if (s == 1) { dy1 = -1; dx1 = 1;  dy2 = 1; dx2 = -1; }
        else if (s == 2) { dy1 = -1; dx1 = 0;  dy2 = 1; dx2 = 0;  }
        else             { dy1 = -1; dx1 = -1; dy2 = 1; dx2 = 1;  }
        int y1 = gy_ + dy1, x1 = gx_ + dx1, y2 = gy_ + dy2, x2 = gx_ + dx2;
        int n1 = (y1 < 0 || y1 >= HH || x1 < 0 || x1 >= WW)
                 ? 0 : (ms[(row + 1 + dy1) * 66 + (lane + 1 + dx1)] >> 2);
        int n2 = (y2 < 0 || y2 >= HH || x2 < 0 || x2 >= WW)
                 ? 0 : (ms[(row + 1 + dy2) * 66 + (lane + 1 + dx2)] >> 2);
        int nms = (mc >= n1 && mc >= n2) ? mc : 0;
        u64 wm = __ballot(nms > 10);
        u64 sm = __ballot(nms > 50);
        if (lane == 0) {
            size_t w = (size_t)n * WPI + gy_ * WPR + tx;
            weakBits[w]   = wm;
            strongBits[w] = sm;
        }
    }
}

// ---- Stage C+D+E: 16 hysteresis iters + 10x10 dilate + 10x10 blur, fused --
// 16 tiles/image (32 rows each) + 26-row halo. Exactness: 16 grow iters
// contaminate 16 rows from the unknown tile edge -> A exact on local rows
// [16, TROWS-17] = [16, 67]; vertical dilate row d (d in [0,41], global
// t0r-5+d) reads horizontally-dilated B rows [d+16, d+25] in [16, 66] ✓.
// Blur of the 32 output rows needs exactly dil rows global [t0r-5, t0r+36]
// (reflect101 at image borders maps back inside this range).
#define TR 32
#define HALO 26
#define TROWS (TR + 2*HALO)    // 84
#define TWORDS (TROWS * WPR)   // 672
__global__ __launch_bounds__(1024) void k_hyst_dil_blur(const u64* __restrict__ strongBits,
                                                        const u64* __restrict__ weakBits,
                                                        unsigned char* __restrict__ E) {
    int tile = blockIdx.x & 15;
    int n    = blockIdx.x >> 4;
    int t0r  = tile * TR;
    int g0   = t0r - HALO;                 // virtual first row of tile
    __shared__ u64 A[TWORDS];
    __shared__ u64 B[TWORDS];
    __shared__ u64 Wl[TWORDS];             // weak bits; reused as D (dilated) later
    __shared__ unsigned char rc[(TR + 10) * 512]; // horizontal blur rowcounts
    int tid = threadIdx.x;

    if (tid < TWORDS) {
        int vr = g0 + (tid >> 3);
        int w  = tid & 7;
        u64 sv = 0, wv = 0;
        if (vr >= 0 && vr < HH) {
            sv = strongBits[(size_t)n * WPI + vr * WPR + w];
            wv = weakBits  [(size_t)n * WPI + vr * WPR + w];
        }
        A[tid] = sv;
        Wl[tid] = wv;
    }
    __syncthreads();

#pragma unroll 1
    for (int it = 0; it < 16; ++it) {
        const u64* src = (it & 1) ? B : A;
        u64*       dst = (it & 1) ? A : B;
        if (tid < TWORDS) {
            int r = tid >> 3;
            int w = tid & 7;
            u64 c  = src[tid];
            u64 up = (r > 0)         ? src[tid - 8] : 0;
            u64 dn = (r < TROWS - 1) ? src[tid + 8] : 0;
            u64 a = c | up | dn;
            u64 pL = 0, pR = 0;
            if (w > 0) {
                u64 cl = src[tid - 1];
                u64 ul = (r > 0)         ? src[tid - 9] : 0;
                u64 dl = (r < TROWS - 1) ? src[tid + 7] : 0;
                pL = cl | ul | dl;
            }
            if (w < 7) {
                u64 cr = src[tid + 1];
                u64 ur = (r > 0)         ? src[tid - 7] : 0;
                u64 dr = (r < TROWS - 1) ? src[tid + 9] : 0;
                pR = cr | ur | dr;
            }
            u64 g = a | (a << 1) | (pL >> 63) | (a >> 1) | (pR << 63);
            dst[tid] = g & Wl[tid];
        }
        __syncthreads();
    }
    // result (after 16 iters) is in A

    // dilate horizontal: window [x-5, x+4]
    if (tid < TWORDS) {
        int w = tid & 7;
        u64 v  = A[tid];
        u64 p  = (w > 0) ? A[tid - 1] : 0;
        u64 nx = (w < 7) ? A[tid + 1] : 0;
        u64 o = v;
#pragma unroll
        for (int d = 1; d <= 5; ++d) o |= (v << d) | (p >> (64 - d));
#pragma unroll
        for (int d = 1; d <= 4; ++d) o |= (v >> d) | (nx << (64 - d));
        B[tid] = o;
    }
    __syncthreads();

    // dilate vertical: window [y-5, y+4], zero-pad beyond image (A/B are 0
    // there). D row d (d in [0,TR+10)) = dil at global row t0r-5+d, local d+21.
    u64* D = Wl;   // weak bits dead now; reuse
    if (tid < (TR + 10) * WPR) {
        int d = tid >> 3;
        int w = tid & 7;
        int r = d + HALO - 5;
        u64 o = 0;
#pragma unroll
        for (int dy = -5; dy <= 4; ++dy) o |= B[(r + dy) * WPR + w];
        D[d * WPR + w] = o;
    }
    __syncthreads();

    // horizontal 10-bit window popcount per pixel (reflect101 at x edges)
    for (int idx = tid; idx < (TR + 10) * 512; idx += 1024) {
        int r = idx >> 9;
        int x = idx & 511;
        int c;
        if (x >= 5 && x <= 507) {
            int b = x - 5, wd = b >> 6, off = b & 63;
            u64 v = D[r * WPR + wd] >> off;
            if (off && wd < 7) v |= D[r * WPR + wd + 1] << (64 - off);
            c = __popcll(v & 0x3FFull);
        } else {
            c = 0;
            for (int dx = -5; dx <= 4; ++dx) {
                int xx = x + dx;
                xx = xx < 0 ? -xx : (xx > WW - 1 ? 2 * (WW - 1) - xx : xx);
                c += (int)((D[r * WPR + (xx >> 6)] >> (xx & 63)) & 1ull);
            }
        }
        rc[idx] = (unsigned char)c;
    }
    __syncthreads();

    // vertical 10-row sum (reflect101 rows at image borders), quantize, store
    // E byte k: edge value = k/255 with k = rint(255*cnt/100) (exact int-val float)
    for (int idx = tid; idx < TR * 512; idx += 1024) {
        int yy = idx >> 9;
        int x  = idx & 511;
        int gy = t0r + yy;
        int sum = 0;
        if (gy >= 5 && gy <= HH - 5) {          // window fully inside image
#pragma unroll
            for (int k = 0; k < 10; ++k) sum += rc[(yy + k) * 512 + x];
        } else {
#pragma unroll
            for (int k = 0; k < 10; ++k) {
                int v  = gy - 5 + k;
                int rv = v < 0 ? -v : (v > HH - 1 ? 2 * (HH - 1) - v : v);
                sum += rc[(rv - (t0r - 5)) * 512 + x];
            }
        }
        float b = rintf((255.0f * (float)sum) / 100.0f);   // round half to even
        E[(size_t)n * HW + gy * WW + x] = (unsigned char)b;
    }
}

// ---- Stage F: per-(n,c) KL partials — no max shift needed -----------------
// |e*pred| <= ~6 so exp() never overflows; Z <= ~5e7 fits float easily.
// loss_nc = Wt/Zt - log Zt + log Zs with Zt=sum e^t, Wt=sum e^t (t-s), Zs=sum e^s
// NOTE (R5 post-mortem): NO device-scope fence/atomic finalize here — the
// __threadfence()+atomicAdd per block cost ~185 us (per-XCD L2 writeback storm
// + contested cross-XCD cache line). Separate tiny final kernel is ~3 us.
__global__ __launch_bounds__(256) void k_kl_partial(const float* __restrict__ S,
                                                    const float* __restrict__ T,
                                                    const unsigned char* __restrict__ E,
                                                    double* __restrict__ partial) {
    int cidx  = blockIdx.x;   // n*CC + c
    int split = blockIdx.y;   // 0..KSPLIT-1
    int n = cidx / CC;
    const float4* Tp = (const float4*)(T + (size_t)cidx * HW + (size_t)split * KCHUNK);
    const float4* Sp = (const float4*)(S + (size_t)cidx * HW + (size_t)split * KCHUNK);
    const uchar4* Ep = (const uchar4*)(E + (size_t)n    * HW + (size_t)split * KCHUNK);
    int tid = threadIdx.x;

    float Zt = 0.0f, Wt = 0.0f, Zs = 0.0f;
#pragma unroll
    for (int k = 0; k < KCHUNK / 4 / 256; ++k) {       // 8 iterations
        int j = k * 256 + tid;
        float4 t4 = Tp[j];
        float4 s4 = Sp[j];
        uchar4 e4 = Ep[j];
#pragma unroll
        for (int u = 0; u < 4; ++u) {
            float e = (float)((&e4.x)[u]) / 255.0f;    // == b/255.0f bit-exact
            float t = e * (&t4.x)[u];
            float s = e * (&s4.x)[u];
            float et = __expf(t);
            Zt += et;
            Wt += et * (t - s);
            Zs += __expf(s);
        }
    }

    // wave-level shuffle reduction (double), then 4-wave LDS combine
    double zt = (double)Zt, wt = (double)Wt, zs = (double)Zs;
#pragma unroll
    for (int off = 32; off > 0; off >>= 1) {
        zt += __shfl_down(zt, off);
        wt += __shfl_down(wt, off);
        zs += __shfl_down(zs, off);
    }
    __shared__ double wr[4][3];
    int wv = tid >> 6, ln = tid & 63;
    if (ln == 0) { wr[wv][0] = zt; wr[wv][1] = wt; wr[wv][2] = zs; }
    __syncthreads();
    if (tid == 0) {
        double* o = partial + ((size_t)cidx * KSPLIT + split) * 3;
        o[0] = wr[0][0] + wr[1][0] + wr[2][0] + wr[3][0];
        o[1] = wr[0][1] + wr[1][1] + wr[2][1] + wr[3][1];
        o[2] = wr[0][2] + wr[1][2] + wr[2][2] + wr[3][2];
    }
}

// ---- Stage G: final reduce -> scalar loss ---------------------------------
__global__ __launch_bounds__(128) void k_kl_final(const double* __restrict__ partial,
                                                  float* __restrict__ out) {
    int tid = threadIdx.x;
    double loss = 0.0;
    if (tid < NB * CC) {
        double Zt = 0.0, Wt = 0.0, Zs = 0.0;
        for (int sp = 0; sp < KSPLIT; ++sp) {
            const double* p = partial + ((size_t)tid * KSPLIT + sp) * 3;
            Zt += p[0]; Wt += p[1]; Zs += p[2];
        }
        loss = Wt / Zt - log(Zt) + log(Zs);
    }
    __shared__ double red[128];
    red[tid] = loss;
    __syncthreads();
    for (int off = 64; off > 0; off >>= 1) {
        if (tid < off) red[tid] += red[tid + off];
        __syncthreads();
    }
    if (tid == 0) out[0] = (float)(red[0] / (double)(NB * CC));  // T^2 = 1
}

extern "C" void kernel_launch(void* const* d_in, const int* in_sizes, int n_in,
                              void* d_out, int out_size, void* d_ws, size_t ws_size,
                              hipStream_t stream) {
    const float* S = (const float*)d_in[0];   // preds_S
    const float* T = (const float*)d_in[1];   // preds_T
    float* out = (float*)d_out;

    char* ws = (char*)d_ws;
    unsigned char* e_buf      = (unsigned char*)(ws);                        // 2 MB (uint8)
    unsigned char* tmap       = (unsigned char*)(ws + (size_t)NHW);          // 2 MB
    u64*           weakBits   = (u64*)(ws + (size_t)NHW * 2);                // 256 KB
    u64*           strongBits = (u64*)(ws + (size_t)NHW * 2 + (NHW/8));      // 256 KB
    double*        partial    = (double*)(ws + (size_t)NHW * 2 + 2*(NHW/8)); // 86 KB

    k_argmax<<<dim3(NHW / 4 / 256), dim3(256), 0, stream>>>(T, (uchar4*)tmap);
    k_sobel_nms<<<dim3(8, 8, NB), dim3(256), 0, stream>>>(tmap, weakBits, strongBits);
    k_hyst_dil_blur<<<dim3(NB * 16), dim3(1024), 0, stream>>>(strongBits, weakBits, e_buf);
    k_kl_partial<<<dim3(NB * CC, KSPLIT), dim3(256), 0, stream>>>(S, T, e_buf, partial);
    k_kl_final<<<1, 128, 0, stream>>>(partial, out);
    (void)in_sizes; (void)n_in; (void)out_size; (void)ws_size;
}